// Round 6
// baseline (669.530 us; speedup 1.0000x reference)
//
#include <hip/hip_runtime.h>

#define DN 128
#define SLOTS 64
#define RCAP 1536   // per-bucket capacity (mean 1024, sd 32 -> +16 sigma)

typedef __attribute__((ext_vector_type(8))) short bf16x8;
typedef __attribute__((ext_vector_type(4))) float f32x4;

__device__ __forceinline__ unsigned short f2bf(float f) {
  unsigned int b = __float_as_uint(f);
  b += 0x7fffu + ((b >> 16) & 1u);
  return (unsigned short)(b >> 16);
}

__device__ __forceinline__ unsigned int pkmul(unsigned int a, unsigned int b) {
  float a0 = __uint_as_float(a << 16);
  float a1 = __uint_as_float(a & 0xffff0000u);
  float b0 = __uint_as_float(b << 16);
  float b1 = __uint_as_float(b & 0xffff0000u);
  return (unsigned int)f2bf(a0 * b0) | ((unsigned int)f2bf(a1 * b1) << 16);
}

// ---------------- phase A: coarse bucket scatter + fused emb gather ----------
// Receiver buckets: entry = (r&63)<<17 | s  (s < 2^17). Sender buckets: byte s&63.
__device__ __forceinline__ void edge_scatter(int s, int r, int* rcnt, int* scnt,
                                             int* __restrict__ rbuck,
                                             unsigned char* __restrict__ sbuck) {
  int rb = r >> 6;
  int sl = atomicAdd(&rcnt[rb], 1);
  if (sl < RCAP) rbuck[(size_t)rb * RCAP + sl] = ((r & 63) << 17) | s;
  int sb = s >> 6;
  int sl2 = atomicAdd(&scnt[sb], 1);
  if (sl2 < RCAP) sbuck[(size_t)sb * RCAP + sl2] = (unsigned char)(s & 63);
}

__global__ __launch_bounds__(256) void k_bucket(const int* __restrict__ snd,
                                                const int* __restrict__ rcv,
                                                int* rcnt, int* scnt,
                                                int* __restrict__ rbuck,
                                                unsigned char* __restrict__ sbuck,
                                                int E, int fill_blocks,
                                                const int* __restrict__ node_ids,
                                                const float* __restrict__ emb,
                                                unsigned short* __restrict__ x, int n) {
  if ((int)blockIdx.x < fill_blocks) {
    int gid = blockIdx.x * 256 + threadIdx.x;
    int base = gid * 4;
    if (base + 4 <= E) {
      int4 s4 = *(const int4*)(snd + base);
      int4 r4 = *(const int4*)(rcv + base);
      edge_scatter(s4.x, r4.x, rcnt, scnt, rbuck, sbuck);
      edge_scatter(s4.y, r4.y, rcnt, scnt, rbuck, sbuck);
      edge_scatter(s4.z, r4.z, rcnt, scnt, rbuck, sbuck);
      edge_scatter(s4.w, r4.w, rcnt, scnt, rbuck, sbuck);
    } else {
      for (int e = base; e < E; ++e)
        edge_scatter(snd[e], rcv[e], rcnt, scnt, rbuck, sbuck);
    }
  } else {
    int gblk = blockIdx.x - fill_blocks;
    int total = n * (DN / 4);
#pragma unroll
    for (int kk = 0; kk < 4; ++kk) {
      int idx = gblk * 1024 + kk * 256 + threadIdx.x;
      if (idx >= total) continue;
      int row = idx >> 5;
      int c4 = (idx & 31) << 2;
      int src = node_ids[row];
      float4 v = *(const float4*)(emb + (size_t)src * DN + c4);
      uint2 o;
      o.x = (unsigned int)f2bf(v.x) | ((unsigned int)f2bf(v.y) << 16);
      o.y = (unsigned int)f2bf(v.z) | ((unsigned int)f2bf(v.w) << 16);
      *(uint2*)(x + (size_t)row * DN + c4) = o;
    }
  }
}

// ---------------- phase B: per-bucket fine CSR + degrees + scales ------------
__global__ __launch_bounds__(256) void k_build(const int* __restrict__ rcnt,
                                               const int* __restrict__ scnt,
                                               const int* __restrict__ rbuck,
                                               const unsigned char* __restrict__ sbuck,
                                               int* __restrict__ cnt_r,
                                               int* __restrict__ csr,
                                               float* __restrict__ scale_s,
                                               float* __restrict__ scale_r, int N) {
  __shared__ int cur[64], shist[64];
  int b = blockIdx.x, t = threadIdx.x;
  if (t < 64) { cur[t] = 0; shist[t] = 0; }
  __syncthreads();
  int nb = rcnt[b]; if (nb > RCAP) nb = RCAP;
  int ns = scnt[b]; if (ns > RCAP) ns = RCAP;
  for (int i = t; i < nb; i += 256) {
    int e = rbuck[(size_t)b * RCAP + i];
    int r = (e >> 17) & 63;
    int sl = atomicAdd(&cur[r], 1);
    if (sl < SLOTS) csr[((size_t)b * 64 + r) * SLOTS + sl] = e & 0x1FFFF;
  }
  for (int i = t; i < ns; i += 256) atomicAdd(&shist[sbuck[(size_t)b * RCAP + i]], 1);
  __syncthreads();
  if (t < 64) {
    int node = b * 64 + t;
    if (node < N) {
      int c = cur[t];
      cnt_r[node] = c;
      float cr = (float)(c + 1);
      scale_r[node] = 1.0f / (cr * sqrtf(cr));
      float ds = (float)(shist[t] + 1);
      scale_s[node] = 1.0f / sqrtf(ds);
    }
  }
}

// ---------------- weight transpose+convert (all three weights) ----------------
__global__ __launch_bounds__(256) void k_wt3(const float* __restrict__ W1,
                                             const float* __restrict__ W2,
                                             const float* __restrict__ Wa,
                                             unsigned short* __restrict__ Wt1,
                                             unsigned short* __restrict__ Wt2,
                                             unsigned short* __restrict__ Wat) {
  int idx = blockIdx.x * 256 + threadIdx.x;
  if (idx < 32768) {
    int k = idx >> 7, n = idx & 127;
    Wt1[n * 256 + k] = f2bf(W1[idx]);
  } else if (idx < 65536) {
    int i = idx - 32768;
    int k = i >> 7, n = i & 127;
    Wt2[n * 256 + k] = f2bf(W2[i]);
  } else if (idx < 81920) {
    int i = idx - 65536;
    int k = i >> 7, n = i & 127;
    Wat[n * 128 + k] = f2bf(Wa[i]);
  }
}

// ---------------- per-node gather aggregation (bf16 in/out, fp32 accum) --------
__device__ __forceinline__ void acc4(uint2 u, float wgt, float& ax, float& ay,
                                     float& az, float& aw) {
  ax += __uint_as_float(u.x << 16) * wgt;
  ay += __uint_as_float(u.x & 0xffff0000u) * wgt;
  az += __uint_as_float(u.y << 16) * wgt;
  aw += __uint_as_float(u.y & 0xffff0000u) * wgt;
}

__global__ __launch_bounds__(256) void k_aggregate(const unsigned short* __restrict__ xin,
                                                   const int* __restrict__ cnt_r,
                                                   const int* __restrict__ csr,
                                                   const float* __restrict__ scale_s,
                                                   const float* __restrict__ scale_r,
                                                   unsigned short* __restrict__ out, int n) {
  int hw = threadIdx.x >> 5;
  int lane = threadIdx.x & 31;
  int node = blockIdx.x * 8 + hw;
  if (node >= n) return;
  int start = node * SLOTS;
  int cnt = cnt_r[node];
  if (cnt > SLOTS) cnt = SLOTS;
  int c = lane * 4;
  float ws = scale_s[node];
  float ax = 0.f, ay = 0.f, az = 0.f, aw = 0.f;
  acc4(*(const uint2*)(xin + (size_t)node * DN + c), ws, ax, ay, az, aw);  // self-loop
  int j = 0;
  for (; j + 8 <= cnt; j += 8) {
    int4 ea = *(const int4*)(csr + start + j);
    int4 eb = *(const int4*)(csr + start + j + 4);
    float w0 = scale_s[ea.x], w1 = scale_s[ea.y], w2 = scale_s[ea.z], w3 = scale_s[ea.w];
    float w4 = scale_s[eb.x], w5 = scale_s[eb.y], w6 = scale_s[eb.z], w7 = scale_s[eb.w];
    uint2 u0 = *(const uint2*)(xin + (size_t)ea.x * DN + c);
    uint2 u1 = *(const uint2*)(xin + (size_t)ea.y * DN + c);
    uint2 u2 = *(const uint2*)(xin + (size_t)ea.z * DN + c);
    uint2 u3 = *(const uint2*)(xin + (size_t)ea.w * DN + c);
    uint2 u4 = *(const uint2*)(xin + (size_t)eb.x * DN + c);
    uint2 u5 = *(const uint2*)(xin + (size_t)eb.y * DN + c);
    uint2 u6 = *(const uint2*)(xin + (size_t)eb.z * DN + c);
    uint2 u7 = *(const uint2*)(xin + (size_t)eb.w * DN + c);
    acc4(u0, w0, ax, ay, az, aw);
    acc4(u1, w1, ax, ay, az, aw);
    acc4(u2, w2, ax, ay, az, aw);
    acc4(u3, w3, ax, ay, az, aw);
    acc4(u4, w4, ax, ay, az, aw);
    acc4(u5, w5, ax, ay, az, aw);
    acc4(u6, w6, ax, ay, az, aw);
    acc4(u7, w7, ax, ay, az, aw);
  }
  for (; j + 4 <= cnt; j += 4) {
    int4 ea = *(const int4*)(csr + start + j);
    float w0 = scale_s[ea.x], w1 = scale_s[ea.y], w2 = scale_s[ea.z], w3 = scale_s[ea.w];
    uint2 u0 = *(const uint2*)(xin + (size_t)ea.x * DN + c);
    uint2 u1 = *(const uint2*)(xin + (size_t)ea.y * DN + c);
    uint2 u2 = *(const uint2*)(xin + (size_t)ea.z * DN + c);
    uint2 u3 = *(const uint2*)(xin + (size_t)ea.w * DN + c);
    acc4(u0, w0, ax, ay, az, aw);
    acc4(u1, w1, ax, ay, az, aw);
    acc4(u2, w2, ax, ay, az, aw);
    acc4(u3, w3, ax, ay, az, aw);
  }
  for (; j < cnt; ++j) {
    int s0 = csr[start + j];
    float w0 = scale_s[s0];
    uint2 u0 = *(const uint2*)(xin + (size_t)s0 * DN + c);
    acc4(u0, w0, ax, ay, az, aw);
  }
  float sr = scale_r[node];
  uint2 o;
  o.x = (unsigned int)f2bf(ax * sr) | ((unsigned int)f2bf(ay * sr) << 16);
  o.y = (unsigned int)f2bf(az * sr) | ((unsigned int)f2bf(aw * sr) << 16);
  *(uint2*)(out + (size_t)node * DN + c) = o;
}

// ---------------- layer GEMM (MFMA bf16): C = relu?( [A1|A2] @ W + bias ) -------
__global__ __launch_bounds__(256) void k_gemm(const unsigned short* __restrict__ A1,
                                              const unsigned short* __restrict__ A2,
                                              const unsigned short* __restrict__ Wt,  // [128][256] bf16
                                              const float* __restrict__ bias,
                                              unsigned short* __restrict__ C,
                                              int nrows, int dorelu) {
  __shared__ unsigned short a_sh[128 * 40];  // [row][k], stride 40 (pad)
  __shared__ unsigned short b_sh[128 * 40];  // [n][k], stride 40
  int t = threadIdx.x;
  int w = t >> 6, l = t & 63, quad = l >> 4, lm = l & 15;
  int row0 = blockIdx.x * 128;
  f32x4 acc[2][8];
#pragma unroll
  for (int i = 0; i < 2; ++i)
#pragma unroll
    for (int j = 0; j < 8; ++j) acc[i][j] = (f32x4){0.f, 0.f, 0.f, 0.f};

  for (int ch = 0; ch < 8; ++ch) {
    const unsigned short* src = (ch < 4) ? A1 : A2;
    int kb = (ch & 3) * 32;
    int kk = ch * 32;
#pragma unroll
    for (int rep = 0; rep < 2; ++rep) {
      int idx = t + rep * 256;
      int r = idx >> 2, q = idx & 3;
      int gr = row0 + r;
      if (gr > nrows - 1) gr = nrows - 1;
      *(uint4*)&a_sh[r * 40 + q * 8] = *(const uint4*)(src + (size_t)gr * DN + kb + q * 8);
      int nn = idx >> 2;
      *(uint4*)&b_sh[nn * 40 + q * 8] = *(const uint4*)(Wt + (size_t)nn * 256 + kk + q * 8);
    }
    __syncthreads();
    bf16x8 af0 = *(bf16x8*)&a_sh[(w * 32 + lm) * 40 + quad * 8];
    bf16x8 af1 = *(bf16x8*)&a_sh[(w * 32 + 16 + lm) * 40 + quad * 8];
#pragma unroll
    for (int nt = 0; nt < 8; ++nt) {
      bf16x8 bfr = *(bf16x8*)&b_sh[(nt * 16 + lm) * 40 + quad * 8];
      acc[0][nt] = __builtin_amdgcn_mfma_f32_16x16x32_bf16(af0, bfr, acc[0][nt], 0, 0, 0);
      acc[1][nt] = __builtin_amdgcn_mfma_f32_16x16x32_bf16(af1, bfr, acc[1][nt], 0, 0, 0);
    }
    __syncthreads();
  }
#pragma unroll
  for (int nt = 0; nt < 8; ++nt) {
    int col = nt * 16 + lm;
    float bv = bias[col];
#pragma unroll
    for (int mt = 0; mt < 2; ++mt)
#pragma unroll
      for (int r = 0; r < 4; ++r) {
        int gr = row0 + w * 32 + mt * 16 + quad * 4 + r;
        if (gr < nrows) {
          float v = acc[mt][nt][r] + bv;
          if (dorelu) v = fmaxf(v, 0.f);
          C[(size_t)gr * DN + col] = f2bf(v);
        }
      }
  }
}

// ---------------- fused link predictor (MFMA bf16) ----------------
__global__ __launch_bounds__(256) void k_pred(const unsigned short* __restrict__ h,
                                              const int* __restrict__ pairs,
                                              const unsigned short* __restrict__ Wat,  // [128][128] bf16
                                              const float* __restrict__ ba,
                                              const float* __restrict__ Wb,
                                              const float* __restrict__ bb,
                                              float* __restrict__ scores, int P) {
  __shared__ unsigned short z_sh[128 * 40];
  __shared__ unsigned short b_sh[128 * 40];
  __shared__ int pa[128], pb[128];
  int t = threadIdx.x;
  int p0 = blockIdx.x * 128;
  if (t < 128) {
    int p = p0 + t;
    if (p > P - 1) p = P - 1;
    pa[t] = pairs[2 * p];
    pb[t] = pairs[2 * p + 1];
  }
  __syncthreads();
  int w = t >> 6, l = t & 63, quad = l >> 4, lm = l & 15;
  f32x4 acc[2][8];
#pragma unroll
  for (int i = 0; i < 2; ++i)
#pragma unroll
    for (int j = 0; j < 8; ++j) acc[i][j] = (f32x4){0.f, 0.f, 0.f, 0.f};

  for (int ch = 0; ch < 4; ++ch) {
    int kk = ch * 32;
#pragma unroll
    for (int rep = 0; rep < 2; ++rep) {
      int idx = t + rep * 256;
      int r = idx >> 2, q = idx & 3;
      uint4 ua = *(const uint4*)(h + (size_t)pa[r] * DN + kk + q * 8);
      uint4 ub = *(const uint4*)(h + (size_t)pb[r] * DN + kk + q * 8);
      uint4 o;
      o.x = pkmul(ua.x, ub.x);
      o.y = pkmul(ua.y, ub.y);
      o.z = pkmul(ua.z, ub.z);
      o.w = pkmul(ua.w, ub.w);
      *(uint4*)&z_sh[r * 40 + q * 8] = o;
      *(uint4*)&b_sh[r * 40 + q * 8] = *(const uint4*)(Wat + (size_t)r * 128 + kk + q * 8);
    }
    __syncthreads();
    bf16x8 af0 = *(bf16x8*)&z_sh[(w * 32 + lm) * 40 + quad * 8];
    bf16x8 af1 = *(bf16x8*)&z_sh[(w * 32 + 16 + lm) * 40 + quad * 8];
#pragma unroll
    for (int nt = 0; nt < 8; ++nt) {
      bf16x8 bfr = *(bf16x8*)&b_sh[(nt * 16 + lm) * 40 + quad * 8];
      acc[0][nt] = __builtin_amdgcn_mfma_f32_16x16x32_bf16(af0, bfr, acc[0][nt], 0, 0, 0);
      acc[1][nt] = __builtin_amdgcn_mfma_f32_16x16x32_bf16(af1, bfr, acc[1][nt], 0, 0, 0);
    }
    __syncthreads();
  }
  float s[2][4] = {{0.f, 0.f, 0.f, 0.f}, {0.f, 0.f, 0.f, 0.f}};
#pragma unroll
  for (int nt = 0; nt < 8; ++nt) {
    int col = nt * 16 + lm;
    float bav = ba[col];
    float wbv = Wb[col];
#pragma unroll
    for (int mt = 0; mt < 2; ++mt)
#pragma unroll
      for (int r = 0; r < 4; ++r)
        s[mt][r] += fmaxf(acc[mt][nt][r] + bav, 0.f) * wbv;
  }
#pragma unroll
  for (int mask = 1; mask <= 8; mask <<= 1)
#pragma unroll
    for (int mt = 0; mt < 2; ++mt)
#pragma unroll
      for (int r = 0; r < 4; ++r) s[mt][r] += __shfl_xor(s[mt][r], mask);
  if (lm == 0) {
    float bbv = bb[0];
#pragma unroll
    for (int mt = 0; mt < 2; ++mt)
#pragma unroll
      for (int r = 0; r < 4; ++r) {
        int p = p0 + w * 32 + mt * 16 + quad * 4 + r;
        if (p < P) scores[p] = s[mt][r] + bbv;
      }
  }
}

extern "C" void kernel_launch(void* const* d_in, const int* in_sizes, int n_in,
                              void* d_out, int out_size, void* d_ws, size_t ws_size,
                              hipStream_t stream) {
  const int* node_ids = (const int*)d_in[0];
  const int* senders = (const int*)d_in[1];
  const int* receivers = (const int*)d_in[2];
  const int* pairs = (const int*)d_in[3];
  const float* emb = (const float*)d_in[4];
  const float* W1 = (const float*)d_in[5];
  const float* b1 = (const float*)d_in[6];
  const float* W2 = (const float*)d_in[7];
  const float* b2 = (const float*)d_in[8];
  const float* Wa = (const float*)d_in[9];
  const float* ba = (const float*)d_in[10];
  const float* Wb = (const float*)d_in[11];
  const float* bb = (const float*)d_in[12];
  float* scores = (float*)d_out;

  int N = in_sizes[0];
  int E = in_sizes[1];
  int P = in_sizes[3] / 2;
  int NB = (N + 63) >> 6;   // coarse buckets

  char* w = (char*)d_ws;
  auto alloc = [&](size_t bytes) {
    void* p = (void*)w;
    w += (bytes + 255) & ~(size_t)255;
    return p;
  };
  unsigned short* xb = (unsigned short*)alloc((size_t)N * DN * 2);  // x, later h
  unsigned short* ub = (unsigned short*)alloc((size_t)N * DN * 2);  // aggregated msgs
  unsigned short* y1b = (unsigned short*)alloc((size_t)N * DN * 2); // layer-1 out
  unsigned short* Wt1 = (unsigned short*)alloc(256 * 128 * 2);
  unsigned short* Wt2 = (unsigned short*)alloc(256 * 128 * 2);
  unsigned short* Wat = (unsigned short*)alloc(128 * 128 * 2);
  float* scale_s = (float*)alloc((size_t)N * 4);
  float* scale_r = (float*)alloc((size_t)N * 4);
  int* cnt_r = (int*)alloc((size_t)N * 4);
  int* bcnt = (int*)alloc((size_t)2 * NB * 4);   // rcnt | scnt
  int* rcnt = bcnt;
  int* scnt = bcnt + NB;
  int* rbuck = (int*)alloc((size_t)NB * RCAP * 4);
  unsigned char* sbuck = (unsigned char*)alloc((size_t)NB * RCAP);
  int* csr = (int*)alloc((size_t)N * SLOTS * 4);

  // weight prep (single launch)
  k_wt3<<<(81920 + 255) / 256, 256, 0, stream>>>(W1, W2, Wa, Wt1, Wt2, Wat);

  // phase A: coarse bucket scatter + emb gather
  hipMemsetAsync(bcnt, 0, (size_t)2 * NB * 4, stream);
  int fill_blocks = (E / 4 + 255) / 256;
  int gather_blocks = (N * (DN / 4) + 1023) / 1024;
  k_bucket<<<fill_blocks + gather_blocks, 256, 0, stream>>>(
      senders, receivers, rcnt, scnt, rbuck, sbuck, E, fill_blocks,
      node_ids, emb, xb, N);

  // phase B: fine CSR + scales (LDS atomics only)
  k_build<<<NB, 256, 0, stream>>>(rcnt, scnt, rbuck, sbuck, cnt_r, csr,
                                  scale_s, scale_r, N);

  // layer 1
  k_aggregate<<<(N + 7) / 8, 256, 0, stream>>>(xb, cnt_r, csr, scale_s, scale_r, ub, N);
  k_gemm<<<(N + 127) / 128, 256, 0, stream>>>(xb, ub, Wt1, b1, y1b, N, 1);

  // layer 2 (h into xb; x dead)
  k_aggregate<<<(N + 7) / 8, 256, 0, stream>>>(y1b, cnt_r, csr, scale_s, scale_r, ub, N);
  k_gemm<<<(N + 127) / 128, 256, 0, stream>>>(y1b, ub, Wt2, b2, xb, N, 0);

  // predictor
  k_pred<<<(P + 127) / 128, 256, 0, stream>>>(xb, pairs, Wat, ba, Wb, bb, scores, P);
}

// Round 7
// 432.491 us; speedup vs baseline: 1.5481x; 1.5481x over previous
//
#include <hip/hip_runtime.h>

#define DN 128
#define SLOTS 64
#define RSZ 512      // nodes per range (power of 2)
#define NCHUNK 256   // edge chunks (= routing blocks)
#define CAP 96       // per (range,chunk) segment capacity; mean 32, +11 sigma

typedef __attribute__((ext_vector_type(8))) short bf16x8;
typedef __attribute__((ext_vector_type(4))) float f32x4;

__device__ __forceinline__ unsigned short f2bf(float f) {
  unsigned int b = __float_as_uint(f);
  b += 0x7fffu + ((b >> 16) & 1u);
  return (unsigned short)(b >> 16);
}

__device__ __forceinline__ unsigned int pkmul(unsigned int a, unsigned int b) {
  float a0 = __uint_as_float(a << 16);
  float a1 = __uint_as_float(a & 0xffff0000u);
  float b0 = __uint_as_float(b << 16);
  float b1 = __uint_as_float(b & 0xffff0000u);
  return (unsigned int)f2bf(a0 * b0) | ((unsigned int)f2bf(a1 * b1) << 16);
}

// ---------------- phase A: atomic-free edge routing + fused emb gather --------
// Blocks [0, NCHUNK): route edges of chunk b into per-(range,chunk) segments
// using LDS cursors. Blocks [NCHUNK, ...): x = bf16(emb[node_ids]).
__global__ __launch_bounds__(256) void k_route(const int* __restrict__ snd,
                                               const int* __restrict__ rcv,
                                               int* __restrict__ rbuf,
                                               unsigned short* __restrict__ sbuf,
                                               int* __restrict__ rc, int* __restrict__ sc,
                                               int E, int CE, int NR,
                                               const int* __restrict__ node_ids,
                                               const float* __restrict__ emb,
                                               unsigned short* __restrict__ x, int n) {
  if ((int)blockIdx.x < NCHUNK) {
    __shared__ int rcur[256], scur[256];
    int t = threadIdx.x;
    int chunk = blockIdx.x;
    rcur[t] = 0;
    scur[t] = 0;
    __syncthreads();
    int e0 = chunk * CE;
    int e1 = e0 + CE;
    if (e1 > E) e1 = E;
    for (int e = e0 + t; e < e1; e += 256) {
      int s = snd[e], r = rcv[e];
      int rr = r >> 9;
      int pos = atomicAdd(&rcur[rr], 1);
      if (pos < CAP)
        rbuf[((size_t)rr * NCHUNK + chunk) * CAP + pos] = ((r & (RSZ - 1)) << 17) | s;
      int sr = s >> 9;
      int pos2 = atomicAdd(&scur[sr], 1);
      if (pos2 < CAP)
        sbuf[((size_t)sr * NCHUNK + chunk) * CAP + pos2] = (unsigned short)(s & (RSZ - 1));
    }
    __syncthreads();
    if (t < NR) {
      rc[t * NCHUNK + chunk] = rcur[t];
      sc[t * NCHUNK + chunk] = scur[t];
    }
  } else {
    int gblk = blockIdx.x - NCHUNK;
    int total = n * (DN / 4);
#pragma unroll
    for (int kk = 0; kk < 4; ++kk) {
      int idx = gblk * 1024 + kk * 256 + threadIdx.x;
      if (idx >= total) continue;
      int row = idx >> 5;
      int c4 = (idx & 31) << 2;
      int src = node_ids[row];
      float4 v = *(const float4*)(emb + (size_t)src * DN + c4);
      uint2 o;
      o.x = (unsigned int)f2bf(v.x) | ((unsigned int)f2bf(v.y) << 16);
      o.y = (unsigned int)f2bf(v.z) | ((unsigned int)f2bf(v.w) << 16);
      *(uint2*)(x + (size_t)row * DN + c4) = o;
    }
  }
}

// ---------------- phase B: per-range CSR + degrees + scales (LDS atomics) -----
__global__ __launch_bounds__(256) void k_build2(const int* __restrict__ rbuf,
                                                const unsigned short* __restrict__ sbuf,
                                                const int* __restrict__ rc,
                                                const int* __restrict__ sc,
                                                int* __restrict__ cnt_r,
                                                int* __restrict__ csr,
                                                float* __restrict__ scale_s,
                                                float* __restrict__ scale_r, int N) {
  __shared__ int cur[RSZ], hist[RSZ];
  int g = blockIdx.x, t = threadIdx.x;
  cur[t] = 0;
  cur[t + 256] = 0;
  hist[t] = 0;
  hist[t + 256] = 0;
  __syncthreads();
  // thread t consumes segment (g, chunk=t)
  {
    int cnt = rc[g * NCHUNK + t];
    if (cnt > CAP) cnt = CAP;
    const int* row = rbuf + ((size_t)g * NCHUNK + t) * CAP;
    for (int i = 0; i < cnt; ++i) {
      int e = row[i];
      int rl = e >> 17;
      int s = e & 0x1FFFF;
      int sl = atomicAdd(&cur[rl], 1);
      if (sl < SLOTS) csr[((size_t)g * RSZ + rl) * SLOTS + sl] = s;
    }
    int cnt2 = sc[g * NCHUNK + t];
    if (cnt2 > CAP) cnt2 = CAP;
    const unsigned short* row2 = sbuf + ((size_t)g * NCHUNK + t) * CAP;
    for (int i = 0; i < cnt2; ++i) atomicAdd(&hist[row2[i]], 1);
  }
  __syncthreads();
#pragma unroll
  for (int k = 0; k < 2; ++k) {
    int tt = t + k * 256;
    int node = g * RSZ + tt;
    if (node < N) {
      int c = cur[tt];
      cnt_r[node] = c;
      float cr = (float)(c + 1);
      scale_r[node] = 1.0f / (cr * sqrtf(cr));
      float ds = (float)(hist[tt] + 1);
      scale_s[node] = 1.0f / sqrtf(ds);
    }
  }
}

// ---------------- weight transpose+convert (all three weights) ----------------
__global__ __launch_bounds__(256) void k_wt3(const float* __restrict__ W1,
                                             const float* __restrict__ W2,
                                             const float* __restrict__ Wa,
                                             unsigned short* __restrict__ Wt1,
                                             unsigned short* __restrict__ Wt2,
                                             unsigned short* __restrict__ Wat) {
  int idx = blockIdx.x * 256 + threadIdx.x;
  if (idx < 32768) {
    int k = idx >> 7, n = idx & 127;
    Wt1[n * 256 + k] = f2bf(W1[idx]);
  } else if (idx < 65536) {
    int i = idx - 32768;
    int k = i >> 7, n = i & 127;
    Wt2[n * 256 + k] = f2bf(W2[i]);
  } else if (idx < 81920) {
    int i = idx - 65536;
    int k = i >> 7, n = i & 127;
    Wat[n * 128 + k] = f2bf(Wa[i]);
  }
}

// ---------------- per-node gather aggregation (bf16 in/out, fp32 accum) --------
__device__ __forceinline__ void acc4(uint2 u, float wgt, float& ax, float& ay,
                                     float& az, float& aw) {
  ax += __uint_as_float(u.x << 16) * wgt;
  ay += __uint_as_float(u.x & 0xffff0000u) * wgt;
  az += __uint_as_float(u.y << 16) * wgt;
  aw += __uint_as_float(u.y & 0xffff0000u) * wgt;
}

__global__ __launch_bounds__(256) void k_aggregate(const unsigned short* __restrict__ xin,
                                                   const int* __restrict__ cnt_r,
                                                   const int* __restrict__ csr,
                                                   const float* __restrict__ scale_s,
                                                   const float* __restrict__ scale_r,
                                                   unsigned short* __restrict__ out, int n) {
  int hw = threadIdx.x >> 5;
  int lane = threadIdx.x & 31;
  int node = blockIdx.x * 8 + hw;
  if (node >= n) return;
  int start = node * SLOTS;
  int cnt = cnt_r[node];
  if (cnt > SLOTS) cnt = SLOTS;
  int c = lane * 4;
  float ws = scale_s[node];
  float ax = 0.f, ay = 0.f, az = 0.f, aw = 0.f;
  acc4(*(const uint2*)(xin + (size_t)node * DN + c), ws, ax, ay, az, aw);  // self-loop
  int j = 0;
  for (; j + 8 <= cnt; j += 8) {
    int4 ea = *(const int4*)(csr + start + j);
    int4 eb = *(const int4*)(csr + start + j + 4);
    float w0 = scale_s[ea.x], w1 = scale_s[ea.y], w2 = scale_s[ea.z], w3 = scale_s[ea.w];
    float w4 = scale_s[eb.x], w5 = scale_s[eb.y], w6 = scale_s[eb.z], w7 = scale_s[eb.w];
    uint2 u0 = *(const uint2*)(xin + (size_t)ea.x * DN + c);
    uint2 u1 = *(const uint2*)(xin + (size_t)ea.y * DN + c);
    uint2 u2 = *(const uint2*)(xin + (size_t)ea.z * DN + c);
    uint2 u3 = *(const uint2*)(xin + (size_t)ea.w * DN + c);
    uint2 u4 = *(const uint2*)(xin + (size_t)eb.x * DN + c);
    uint2 u5 = *(const uint2*)(xin + (size_t)eb.y * DN + c);
    uint2 u6 = *(const uint2*)(xin + (size_t)eb.z * DN + c);
    uint2 u7 = *(const uint2*)(xin + (size_t)eb.w * DN + c);
    acc4(u0, w0, ax, ay, az, aw);
    acc4(u1, w1, ax, ay, az, aw);
    acc4(u2, w2, ax, ay, az, aw);
    acc4(u3, w3, ax, ay, az, aw);
    acc4(u4, w4, ax, ay, az, aw);
    acc4(u5, w5, ax, ay, az, aw);
    acc4(u6, w6, ax, ay, az, aw);
    acc4(u7, w7, ax, ay, az, aw);
  }
  for (; j + 4 <= cnt; j += 4) {
    int4 ea = *(const int4*)(csr + start + j);
    float w0 = scale_s[ea.x], w1 = scale_s[ea.y], w2 = scale_s[ea.z], w3 = scale_s[ea.w];
    uint2 u0 = *(const uint2*)(xin + (size_t)ea.x * DN + c);
    uint2 u1 = *(const uint2*)(xin + (size_t)ea.y * DN + c);
    uint2 u2 = *(const uint2*)(xin + (size_t)ea.z * DN + c);
    uint2 u3 = *(const uint2*)(xin + (size_t)ea.w * DN + c);
    acc4(u0, w0, ax, ay, az, aw);
    acc4(u1, w1, ax, ay, az, aw);
    acc4(u2, w2, ax, ay, az, aw);
    acc4(u3, w3, ax, ay, az, aw);
  }
  for (; j < cnt; ++j) {
    int s0 = csr[start + j];
    float w0 = scale_s[s0];
    uint2 u0 = *(const uint2*)(xin + (size_t)s0 * DN + c);
    acc4(u0, w0, ax, ay, az, aw);
  }
  float sr = scale_r[node];
  uint2 o;
  o.x = (unsigned int)f2bf(ax * sr) | ((unsigned int)f2bf(ay * sr) << 16);
  o.y = (unsigned int)f2bf(az * sr) | ((unsigned int)f2bf(aw * sr) << 16);
  *(uint2*)(out + (size_t)node * DN + c) = o;
}

// ---------------- layer GEMM (MFMA bf16): C = relu?( [A1|A2] @ W + bias ) -------
__global__ __launch_bounds__(256) void k_gemm(const unsigned short* __restrict__ A1,
                                              const unsigned short* __restrict__ A2,
                                              const unsigned short* __restrict__ Wt,  // [128][256] bf16
                                              const float* __restrict__ bias,
                                              unsigned short* __restrict__ C,
                                              int nrows, int dorelu) {
  __shared__ unsigned short a_sh[128 * 40];  // [row][k], stride 40 (pad)
  __shared__ unsigned short b_sh[128 * 40];  // [n][k], stride 40
  int t = threadIdx.x;
  int w = t >> 6, l = t & 63, quad = l >> 4, lm = l & 15;
  int row0 = blockIdx.x * 128;
  f32x4 acc[2][8];
#pragma unroll
  for (int i = 0; i < 2; ++i)
#pragma unroll
    for (int j = 0; j < 8; ++j) acc[i][j] = (f32x4){0.f, 0.f, 0.f, 0.f};

  for (int ch = 0; ch < 8; ++ch) {
    const unsigned short* src = (ch < 4) ? A1 : A2;
    int kb = (ch & 3) * 32;
    int kk = ch * 32;
#pragma unroll
    for (int rep = 0; rep < 2; ++rep) {
      int idx = t + rep * 256;
      int r = idx >> 2, q = idx & 3;
      int gr = row0 + r;
      if (gr > nrows - 1) gr = nrows - 1;
      *(uint4*)&a_sh[r * 40 + q * 8] = *(const uint4*)(src + (size_t)gr * DN + kb + q * 8);
      int nn = idx >> 2;
      *(uint4*)&b_sh[nn * 40 + q * 8] = *(const uint4*)(Wt + (size_t)nn * 256 + kk + q * 8);
    }
    __syncthreads();
    bf16x8 af0 = *(bf16x8*)&a_sh[(w * 32 + lm) * 40 + quad * 8];
    bf16x8 af1 = *(bf16x8*)&a_sh[(w * 32 + 16 + lm) * 40 + quad * 8];
#pragma unroll
    for (int nt = 0; nt < 8; ++nt) {
      bf16x8 bfr = *(bf16x8*)&b_sh[(nt * 16 + lm) * 40 + quad * 8];
      acc[0][nt] = __builtin_amdgcn_mfma_f32_16x16x32_bf16(af0, bfr, acc[0][nt], 0, 0, 0);
      acc[1][nt] = __builtin_amdgcn_mfma_f32_16x16x32_bf16(af1, bfr, acc[1][nt], 0, 0, 0);
    }
    __syncthreads();
  }
#pragma unroll
  for (int nt = 0; nt < 8; ++nt) {
    int col = nt * 16 + lm;
    float bv = bias[col];
#pragma unroll
    for (int mt = 0; mt < 2; ++mt)
#pragma unroll
      for (int r = 0; r < 4; ++r) {
        int gr = row0 + w * 32 + mt * 16 + quad * 4 + r;
        if (gr < nrows) {
          float v = acc[mt][nt][r] + bv;
          if (dorelu) v = fmaxf(v, 0.f);
          C[(size_t)gr * DN + col] = f2bf(v);
        }
      }
  }
}

// ---------------- fused link predictor (MFMA bf16) ----------------
__global__ __launch_bounds__(256) void k_pred(const unsigned short* __restrict__ h,
                                              const int* __restrict__ pairs,
                                              const unsigned short* __restrict__ Wat,  // [128][128] bf16
                                              const float* __restrict__ ba,
                                              const float* __restrict__ Wb,
                                              const float* __restrict__ bb,
                                              float* __restrict__ scores, int P) {
  __shared__ unsigned short z_sh[128 * 40];
  __shared__ unsigned short b_sh[128 * 40];
  __shared__ int pa[128], pb[128];
  int t = threadIdx.x;
  int p0 = blockIdx.x * 128;
  if (t < 128) {
    int p = p0 + t;
    if (p > P - 1) p = P - 1;
    pa[t] = pairs[2 * p];
    pb[t] = pairs[2 * p + 1];
  }
  __syncthreads();
  int w = t >> 6, l = t & 63, quad = l >> 4, lm = l & 15;
  f32x4 acc[2][8];
#pragma unroll
  for (int i = 0; i < 2; ++i)
#pragma unroll
    for (int j = 0; j < 8; ++j) acc[i][j] = (f32x4){0.f, 0.f, 0.f, 0.f};

  for (int ch = 0; ch < 4; ++ch) {
    int kk = ch * 32;
#pragma unroll
    for (int rep = 0; rep < 2; ++rep) {
      int idx = t + rep * 256;
      int r = idx >> 2, q = idx & 3;
      uint4 ua = *(const uint4*)(h + (size_t)pa[r] * DN + kk + q * 8);
      uint4 ub = *(const uint4*)(h + (size_t)pb[r] * DN + kk + q * 8);
      uint4 o;
      o.x = pkmul(ua.x, ub.x);
      o.y = pkmul(ua.y, ub.y);
      o.z = pkmul(ua.z, ub.z);
      o.w = pkmul(ua.w, ub.w);
      *(uint4*)&z_sh[r * 40 + q * 8] = o;
      *(uint4*)&b_sh[r * 40 + q * 8] = *(const uint4*)(Wat + (size_t)r * 128 + kk + q * 8);
    }
    __syncthreads();
    bf16x8 af0 = *(bf16x8*)&z_sh[(w * 32 + lm) * 40 + quad * 8];
    bf16x8 af1 = *(bf16x8*)&z_sh[(w * 32 + 16 + lm) * 40 + quad * 8];
#pragma unroll
    for (int nt = 0; nt < 8; ++nt) {
      bf16x8 bfr = *(bf16x8*)&b_sh[(nt * 16 + lm) * 40 + quad * 8];
      acc[0][nt] = __builtin_amdgcn_mfma_f32_16x16x32_bf16(af0, bfr, acc[0][nt], 0, 0, 0);
      acc[1][nt] = __builtin_amdgcn_mfma_f32_16x16x32_bf16(af1, bfr, acc[1][nt], 0, 0, 0);
    }
    __syncthreads();
  }
  float s[2][4] = {{0.f, 0.f, 0.f, 0.f}, {0.f, 0.f, 0.f, 0.f}};
#pragma unroll
  for (int nt = 0; nt < 8; ++nt) {
    int col = nt * 16 + lm;
    float bav = ba[col];
    float wbv = Wb[col];
#pragma unroll
    for (int mt = 0; mt < 2; ++mt)
#pragma unroll
      for (int r = 0; r < 4; ++r)
        s[mt][r] += fmaxf(acc[mt][nt][r] + bav, 0.f) * wbv;
  }
#pragma unroll
  for (int mask = 1; mask <= 8; mask <<= 1)
#pragma unroll
    for (int mt = 0; mt < 2; ++mt)
#pragma unroll
      for (int r = 0; r < 4; ++r) s[mt][r] += __shfl_xor(s[mt][r], mask);
  if (lm == 0) {
    float bbv = bb[0];
#pragma unroll
    for (int mt = 0; mt < 2; ++mt)
#pragma unroll
      for (int r = 0; r < 4; ++r) {
        int p = p0 + w * 32 + mt * 16 + quad * 4 + r;
        if (p < P) scores[p] = s[mt][r] + bbv;
      }
  }
}

extern "C" void kernel_launch(void* const* d_in, const int* in_sizes, int n_in,
                              void* d_out, int out_size, void* d_ws, size_t ws_size,
                              hipStream_t stream) {
  const int* node_ids = (const int*)d_in[0];
  const int* senders = (const int*)d_in[1];
  const int* receivers = (const int*)d_in[2];
  const int* pairs = (const int*)d_in[3];
  const float* emb = (const float*)d_in[4];
  const float* W1 = (const float*)d_in[5];
  const float* b1 = (const float*)d_in[6];
  const float* W2 = (const float*)d_in[7];
  const float* b2 = (const float*)d_in[8];
  const float* Wa = (const float*)d_in[9];
  const float* ba = (const float*)d_in[10];
  const float* Wb = (const float*)d_in[11];
  const float* bb = (const float*)d_in[12];
  float* scores = (float*)d_out;

  int N = in_sizes[0];
  int E = in_sizes[1];
  int P = in_sizes[3] / 2;
  int NR = (N + RSZ - 1) / RSZ;      // node ranges (196 for N=100k)
  int CE = (E + NCHUNK - 1) / NCHUNK;

  char* w = (char*)d_ws;
  auto alloc = [&](size_t bytes) {
    void* p = (void*)w;
    w += (bytes + 255) & ~(size_t)255;
    return p;
  };
  unsigned short* xb = (unsigned short*)alloc((size_t)N * DN * 2);  // x, later h
  unsigned short* ub = (unsigned short*)alloc((size_t)N * DN * 2);  // aggregated msgs
  unsigned short* y1b = (unsigned short*)alloc((size_t)N * DN * 2); // layer-1 out
  unsigned short* Wt1 = (unsigned short*)alloc(256 * 128 * 2);
  unsigned short* Wt2 = (unsigned short*)alloc(256 * 128 * 2);
  unsigned short* Wat = (unsigned short*)alloc(128 * 128 * 2);
  float* scale_s = (float*)alloc((size_t)N * 4);
  float* scale_r = (float*)alloc((size_t)N * 4);
  int* cnt_r = (int*)alloc((size_t)N * 4);
  int* rbuf = (int*)alloc((size_t)NR * NCHUNK * CAP * 4);
  unsigned short* sbuf = (unsigned short*)alloc((size_t)NR * NCHUNK * CAP * 2);
  int* rc = (int*)alloc((size_t)NR * NCHUNK * 4);
  int* sc = (int*)alloc((size_t)NR * NCHUNK * 4);
  int* csr = (int*)alloc((size_t)NR * RSZ * SLOTS * 4);

  // weight prep
  k_wt3<<<(81920 + 255) / 256, 256, 0, stream>>>(W1, W2, Wa, Wt1, Wt2, Wat);

  // phase A: atomic-free routing + emb gather (no memsets needed)
  int gather_blocks = (N * (DN / 4) + 1023) / 1024;
  k_route<<<NCHUNK + gather_blocks, 256, 0, stream>>>(
      senders, receivers, rbuf, sbuf, rc, sc, E, CE, NR, node_ids, emb, xb, N);

  // phase B: per-range CSR + degrees + scales (LDS atomics only)
  k_build2<<<NR, 256, 0, stream>>>(rbuf, sbuf, rc, sc, cnt_r, csr,
                                   scale_s, scale_r, N);

  // layer 1
  k_aggregate<<<(N + 7) / 8, 256, 0, stream>>>(xb, cnt_r, csr, scale_s, scale_r, ub, N);
  k_gemm<<<(N + 127) / 128, 256, 0, stream>>>(xb, ub, Wt1, b1, y1b, N, 1);

  // layer 2 (h into xb; x dead)
  k_aggregate<<<(N + 7) / 8, 256, 0, stream>>>(y1b, cnt_r, csr, scale_s, scale_r, ub, N);
  k_gemm<<<(N + 127) / 128, 256, 0, stream>>>(y1b, ub, Wt2, b2, xb, N, 0);

  // predictor
  k_pred<<<(P + 127) / 128, 256, 0, stream>>>(xb, pairs, Wat, ba, Wb, bb, scores, P);
}